// Round 1
// baseline (408.474 us; speedup 1.0000x reference)
//
#include <hip/hip_runtime.h>

#define N_NODES 50000
#define N_EDGES 800000
#define N_GRAPHS 512
#define FDIM 128

constexpr int SCAN_TILE = 256;
constexpr int NB = (N_NODES + SCAN_TILE - 1) / SCAN_TILE;  // 196

__global__ void k_init(int* __restrict__ cnt, int* __restrict__ fill,
                       float* __restrict__ out) {
  int i = blockIdx.x * blockDim.x + threadIdx.x;
  if (i < N_NODES) { cnt[i] = 0; fill[i] = 0; }
  if (i < N_GRAPHS * FDIM) out[i] = 0.0f;
}

__global__ void k_count(const int* __restrict__ dst, int* __restrict__ cnt) {
  int e = blockIdx.x * blockDim.x + threadIdx.x;
  if (e < N_EDGES) atomicAdd(&cnt[dst[e]], 1);
}

__global__ void k_scan1(const int* __restrict__ cnt, int* __restrict__ row_ptr,
                        int* __restrict__ blk) {
  __shared__ int s[SCAN_TILE];
  int t = threadIdx.x;
  int i = blockIdx.x * SCAN_TILE + t;
  int v = (i < N_NODES) ? cnt[i] : 0;
  s[t] = v;
  __syncthreads();
  for (int d = 1; d < SCAN_TILE; d <<= 1) {
    int u = (t >= d) ? s[t - d] : 0;
    __syncthreads();
    s[t] += u;
    __syncthreads();
  }
  if (i < N_NODES) row_ptr[i] = s[t] - v;  // block-local exclusive
  if (t == SCAN_TILE - 1) blk[blockIdx.x] = s[t];
}

__global__ void k_scan2(int* __restrict__ blk) {
  __shared__ int s[256];
  int t = threadIdx.x;
  int v = (t < NB) ? blk[t] : 0;
  s[t] = v;
  __syncthreads();
  for (int d = 1; d < 256; d <<= 1) {
    int u = (t >= d) ? s[t - d] : 0;
    __syncthreads();
    s[t] += u;
    __syncthreads();
  }
  if (t < NB) blk[t] = s[t] - v;  // exclusive scan of block sums
}

__global__ void k_scan3(const int* __restrict__ cnt, int* __restrict__ row_ptr,
                        const int* __restrict__ blk, float* __restrict__ dis) {
  int i = blockIdx.x * blockDim.x + threadIdx.x;
  if (i < N_NODES) {
    row_ptr[i] += blk[blockIdx.x];
    dis[i] = rsqrtf((float)(cnt[i] + 1));  // +1 self-loop
  }
  if (i == 0) row_ptr[N_NODES] = N_EDGES;
}

__global__ void k_fill(const int* __restrict__ src, const int* __restrict__ dst,
                       const int* __restrict__ row_ptr, int* __restrict__ fill,
                       const float* __restrict__ dis, int* __restrict__ csr_src,
                       float* __restrict__ csr_norm) {
  int e = blockIdx.x * blockDim.x + threadIdx.x;
  if (e >= N_EDGES) return;
  int s = src[e], d = dst[e];
  int pos = row_ptr[d] + atomicAdd(&fill[d], 1);
  csr_src[pos] = s;
  csr_norm[pos] = dis[s] * dis[d];
}

__global__ void k_gather(const int* __restrict__ x_type,
                         const float* __restrict__ emb, float* __restrict__ x) {
  int t = blockIdx.x * blockDim.x + threadIdx.x;  // N_NODES*32 threads
  int row = t >> 5, c4 = t & 31;
  if (row >= N_NODES) return;
  const float4* s = (const float4*)(emb + (size_t)x_type[row] * FDIM);
  ((float4*)(x + (size_t)row * FDIM))[c4] = s[c4];
}

// One wave (64 lanes) per node; float2 per lane covers 128 features.
__global__ void k_agg(const float* __restrict__ x, float* __restrict__ y,
                      const int* __restrict__ row_ptr,
                      const int* __restrict__ csr_src,
                      const float* __restrict__ csr_norm,
                      const float* __restrict__ dis) {
  int gid = blockIdx.x * blockDim.x + threadIdx.x;
  int node = gid >> 6;
  int lane = gid & 63;
  if (node >= N_NODES) return;
  float di = dis[node];
  float w0 = di * di;  // self-loop norm
  float2 v = ((const float2*)(x + (size_t)node * FDIM))[lane];
  float2 acc = make_float2(v.x * w0, v.y * w0);
  int beg = row_ptr[node], end = row_ptr[node + 1];
  for (int j = beg; j < end; ++j) {
    int s = csr_src[j];          // wave-uniform load
    float w = csr_norm[j];       // wave-uniform load
    float2 u = ((const float2*)(x + (size_t)s * FDIM))[lane];
    acc.x = fmaf(u.x, w, acc.x);
    acc.y = fmaf(u.y, w, acc.y);
  }
  ((float2*)(y + (size_t)node * FDIM))[lane] = acc;
}

// Block: 256 threads -> 32 rows x 128 cols tile. Thread (tr,tc): rows tr+8i,
// cols tc+32j, 4x4 register micro-tile. W staged in LDS in two 64-k chunks.
template <int RELU, int POOL>
__global__ __launch_bounds__(256) void k_gemm(
    const float* __restrict__ x, const float* __restrict__ W,
    const float* __restrict__ bias, float* __restrict__ y,
    const int* __restrict__ batch, float* __restrict__ out) {
  __shared__ float Ws[64][FDIM];
  __shared__ float xs[32][FDIM];
  int t = threadIdx.x;
  int tc = t & 31;
  int tr = t >> 5;
  int row0 = blockIdx.x * 32;

  for (int idx = t; idx < 32 * 32; idx += 256) {
    int r = idx >> 5, c4 = idx & 31;
    int gr = row0 + r;
    float4 v = make_float4(0.f, 0.f, 0.f, 0.f);
    if (gr < N_NODES) v = ((const float4*)(x + (size_t)gr * FDIM))[c4];
    *(float4*)&xs[r][c4 * 4] = v;
  }
  float bv[4];
#pragma unroll
  for (int j = 0; j < 4; ++j) bv[j] = bias[tc + 32 * j];

  float acc[4][4] = {};
  for (int k0 = 0; k0 < FDIM; k0 += 64) {
    __syncthreads();
    for (int idx = t; idx < 64 * FDIM; idx += 256) {
      int kk = idx >> 7, c = idx & 127;
      Ws[kk][c] = W[(size_t)(k0 + kk) * FDIM + c];
    }
    __syncthreads();
#pragma unroll 16
    for (int kk = 0; kk < 64; ++kk) {
      float xv[4], wv[4];
#pragma unroll
      for (int i = 0; i < 4; ++i) xv[i] = xs[tr + 8 * i][k0 + kk];
#pragma unroll
      for (int j = 0; j < 4; ++j) wv[j] = Ws[kk][tc + 32 * j];
#pragma unroll
      for (int i = 0; i < 4; ++i)
#pragma unroll
        for (int j = 0; j < 4; ++j) acc[i][j] = fmaf(xv[i], wv[j], acc[i][j]);
    }
  }

#pragma unroll
  for (int i = 0; i < 4; ++i) {
    int r = row0 + tr + 8 * i;
    if (r >= N_NODES) continue;
    if (POOL) {
      int g = batch[r];
#pragma unroll
      for (int j = 0; j < 4; ++j) {
        float v = acc[i][j] + bv[j];
        atomicAdd(&out[(size_t)g * FDIM + tc + 32 * j], v);
      }
    } else {
#pragma unroll
      for (int j = 0; j < 4; ++j) {
        float v = acc[i][j] + bv[j];
        if (RELU) v = fmaxf(v, 0.f);
        y[(size_t)r * FDIM + tc + 32 * j] = v;
      }
    }
  }
}

extern "C" void kernel_launch(void* const* d_in, const int* in_sizes, int n_in,
                              void* d_out, int out_size, void* d_ws,
                              size_t ws_size, hipStream_t stream) {
  const int* x_type = (const int*)d_in[0];
  const int* edge_index = (const int*)d_in[1];
  const int* batch = (const int*)d_in[2];
  const float* emb = (const float*)d_in[3];
  const float* W1 = (const float*)d_in[4];
  const float* b1 = (const float*)d_in[5];
  const float* W2 = (const float*)d_in[6];
  const float* b2 = (const float*)d_in[7];
  float* out = (float*)d_out;

  const int* src = edge_index;            // edge_index[0][:]
  const int* dst = edge_index + N_EDGES;  // edge_index[1][:]

  char* p = (char*)d_ws;
  size_t off = 0;
  auto alloc = [&](size_t bytes) {
    void* r = p + off;
    off = (off + bytes + 255) & ~(size_t)255;
    return r;
  };
  float* dis = (float*)alloc(N_NODES * 4);
  int* cnt = (int*)alloc(N_NODES * 4);
  int* row_ptr = (int*)alloc((N_NODES + 1) * 4);
  int* fill = (int*)alloc(N_NODES * 4);
  int* blk = (int*)alloc(1024);
  int* csr_src = (int*)alloc((size_t)N_EDGES * 4);
  float* csr_norm = (float*)alloc((size_t)N_EDGES * 4);
  float* bufA = (float*)alloc((size_t)N_NODES * FDIM * 4);
  float* bufB = (float*)alloc((size_t)N_NODES * FDIM * 4);
  (void)ws_size;

  k_init<<<256, 256, 0, stream>>>(cnt, fill, out);
  k_count<<<(N_EDGES + 255) / 256, 256, 0, stream>>>(dst, cnt);
  k_scan1<<<NB, 256, 0, stream>>>(cnt, row_ptr, blk);
  k_scan2<<<1, 256, 0, stream>>>(blk);
  k_scan3<<<NB, 256, 0, stream>>>(cnt, row_ptr, blk, dis);
  k_fill<<<(N_EDGES + 255) / 256, 256, 0, stream>>>(src, dst, row_ptr, fill,
                                                    dis, csr_src, csr_norm);
  k_gather<<<(N_NODES * 32 + 255) / 256, 256, 0, stream>>>(x_type, emb, bufA);
  k_agg<<<(N_NODES * 64 + 255) / 256, 256, 0, stream>>>(bufA, bufB, row_ptr,
                                                        csr_src, csr_norm, dis);
  k_gemm<1, 0><<<(N_NODES + 31) / 32, 256, 0, stream>>>(bufB, W1, b1, bufA,
                                                        batch, out);
  k_agg<<<(N_NODES * 64 + 255) / 256, 256, 0, stream>>>(bufA, bufB, row_ptr,
                                                        csr_src, csr_norm, dis);
  k_gemm<0, 1><<<(N_NODES + 31) / 32, 256, 0, stream>>>(bufB, W2, b2, bufA,
                                                        batch, out);
}

// Round 2
// 274.641 us; speedup vs baseline: 1.4873x; 1.4873x over previous
//
#include <hip/hip_runtime.h>

#define N_NODES 50000
#define N_EDGES 800000
#define N_GRAPHS 512
#define FDIM 128

constexpr int SCAN_TILE = 256;
constexpr int NB = (N_NODES + SCAN_TILE - 1) / SCAN_TILE;  // 196

typedef __bf16 bf16x8 __attribute__((ext_vector_type(8)));
typedef float f32x4 __attribute__((ext_vector_type(4)));

__device__ __forceinline__ unsigned short f2bf(float f) {
  unsigned int u = __float_as_uint(f);
  unsigned int r = (u + 0x7FFFu + ((u >> 16) & 1u)) >> 16;
  return (unsigned short)r;
}
__device__ __forceinline__ float bflo(unsigned int v) {
  return __uint_as_float(v << 16);
}
__device__ __forceinline__ float bfhi(unsigned int v) {
  return __uint_as_float(v & 0xFFFF0000u);
}

__global__ void k_init(int* __restrict__ cnt, int* __restrict__ fill,
                       float* __restrict__ out) {
  int i = blockIdx.x * blockDim.x + threadIdx.x;
  if (i < N_NODES) { cnt[i] = 0; fill[i] = 0; }
  if (i < N_GRAPHS * FDIM) out[i] = 0.0f;
}

__global__ void k_count(const int* __restrict__ dst, int* __restrict__ cnt) {
  int e = blockIdx.x * blockDim.x + threadIdx.x;
  if (e < N_EDGES) atomicAdd(&cnt[dst[e]], 1);
}

__global__ void k_scan1(const int* __restrict__ cnt, int* __restrict__ row_ptr,
                        int* __restrict__ blk) {
  __shared__ int s[SCAN_TILE];
  int t = threadIdx.x;
  int i = blockIdx.x * SCAN_TILE + t;
  int v = (i < N_NODES) ? cnt[i] : 0;
  s[t] = v;
  __syncthreads();
  for (int d = 1; d < SCAN_TILE; d <<= 1) {
    int u = (t >= d) ? s[t - d] : 0;
    __syncthreads();
    s[t] += u;
    __syncthreads();
  }
  if (i < N_NODES) row_ptr[i] = s[t] - v;
  if (t == SCAN_TILE - 1) blk[blockIdx.x] = s[t];
}

__global__ void k_scan2(int* __restrict__ blk) {
  __shared__ int s[256];
  int t = threadIdx.x;
  int v = (t < NB) ? blk[t] : 0;
  s[t] = v;
  __syncthreads();
  for (int d = 1; d < 256; d <<= 1) {
    int u = (t >= d) ? s[t - d] : 0;
    __syncthreads();
    s[t] += u;
    __syncthreads();
  }
  if (t < NB) blk[t] = s[t] - v;
}

__global__ void k_scan3(const int* __restrict__ cnt, int* __restrict__ row_ptr,
                        const int* __restrict__ blk, float* __restrict__ dis) {
  int i = blockIdx.x * blockDim.x + threadIdx.x;
  if (i < N_NODES) {
    row_ptr[i] += blk[blockIdx.x];
    dis[i] = rsqrtf((float)(cnt[i] + 1));
  }
  if (i == 0) row_ptr[N_NODES] = N_EDGES;
}

__global__ void k_fill(const int* __restrict__ src, const int* __restrict__ dst,
                       const int* __restrict__ row_ptr, int* __restrict__ fill,
                       const float* __restrict__ dis, int2* __restrict__ csr) {
  int e = blockIdx.x * blockDim.x + threadIdx.x;
  if (e >= N_EDGES) return;
  int s = src[e], d = dst[e];
  int pos = row_ptr[d] + atomicAdd(&fill[d], 1);
  csr[pos] = make_int2(s, __float_as_int(dis[s] * dis[d]));
}

// W [128x128] f32 row-major(k,n) -> Wt bf16 [n][k ^ ((n&7)<<3)] (swizzled)
__global__ void k_prep_w(const float* __restrict__ W0,
                         const float* __restrict__ W1,
                         unsigned short* __restrict__ Wt0,
                         unsigned short* __restrict__ Wt1) {
  int id = blockIdx.x * blockDim.x + threadIdx.x;  // 32768
  const float* W = (id >> 14) ? W1 : W0;
  unsigned short* Wt = (id >> 14) ? Wt1 : Wt0;
  int rem = id & 16383;
  int k = rem >> 7, n = rem & 127;
  Wt[n * 128 + (k ^ ((n & 7) << 3))] = f2bf(W[k * 128 + n]);
}

// emb lookup -> bf16 node features (packed 2/uint)
__global__ void k_gather(const int* __restrict__ x_type,
                         const float* __restrict__ emb,
                         unsigned int* __restrict__ x) {
  int t = blockIdx.x * blockDim.x + threadIdx.x;  // N_NODES*64
  int row = t >> 6, c2 = t & 63;
  if (row >= N_NODES) return;
  float2 v = ((const float2*)(emb + (size_t)x_type[row] * FDIM))[c2];
  x[(size_t)row * 64 + c2] = (unsigned int)f2bf(v.x) |
                             ((unsigned int)f2bf(v.y) << 16);
}

// One wave per node; lane holds 2 bf16 features. f32 accumulate.
__global__ void k_agg(const unsigned int* __restrict__ x,
                      unsigned int* __restrict__ y,
                      const int* __restrict__ row_ptr,
                      const int2* __restrict__ csr,
                      const float* __restrict__ dis) {
  int gid = blockIdx.x * blockDim.x + threadIdx.x;
  int node = gid >> 6;
  int lane = gid & 63;
  if (node >= N_NODES) return;
  float di = dis[node];
  float w0 = di * di;
  unsigned int v = x[(size_t)node * 64 + lane];
  float ax = bflo(v) * w0, ay = bfhi(v) * w0;
  int j = row_ptr[node], end = row_ptr[node + 1];
  for (; j + 4 <= end; j += 4) {
    int2 e0 = csr[j], e1 = csr[j + 1], e2 = csr[j + 2], e3 = csr[j + 3];
    unsigned int u0 = x[(size_t)e0.x * 64 + lane];
    unsigned int u1 = x[(size_t)e1.x * 64 + lane];
    unsigned int u2 = x[(size_t)e2.x * 64 + lane];
    unsigned int u3 = x[(size_t)e3.x * 64 + lane];
    float w0_ = __int_as_float(e0.y), w1_ = __int_as_float(e1.y);
    float w2_ = __int_as_float(e2.y), w3_ = __int_as_float(e3.y);
    ax = fmaf(bflo(u0), w0_, ax); ay = fmaf(bfhi(u0), w0_, ay);
    ax = fmaf(bflo(u1), w1_, ax); ay = fmaf(bfhi(u1), w1_, ay);
    ax = fmaf(bflo(u2), w2_, ax); ay = fmaf(bfhi(u2), w2_, ay);
    ax = fmaf(bflo(u3), w3_, ax); ay = fmaf(bfhi(u3), w3_, ay);
  }
  for (; j < end; ++j) {
    int2 e = csr[j];
    unsigned int u = x[(size_t)e.x * 64 + lane];
    float w = __int_as_float(e.y);
    ax = fmaf(bflo(u), w, ax);
    ay = fmaf(bfhi(u), w, ay);
  }
  y[(size_t)node * 64 + lane] = (unsigned int)f2bf(ax) |
                                ((unsigned int)f2bf(ay) << 16);
}

// MFMA GEMM: x[bf16 M x128] @ W[128x128] (+bias, relu / pool).
// Block = 4 waves, each wave 16 rows x 128 cols (8 col-tiles x 4 k-steps).
template <int RELU, int POOL>
__global__ __launch_bounds__(256) void k_gemm(
    const unsigned short* __restrict__ x, const unsigned short* __restrict__ Wt,
    const float* __restrict__ bias, unsigned short* __restrict__ y,
    const int* __restrict__ batch, float* __restrict__ out) {
  __shared__ unsigned short Ws[128 * 128];  // 32 KB, swizzled bf16 W^T
  int t = threadIdx.x;
  // linear stage of pre-swizzled Wt -> LDS (rule 21: swizzle src + read)
  {
    const float4* g = (const float4*)Wt;
    float4* l = (float4*)Ws;
    for (int i = t; i < (128 * 128 * 2) / 16; i += 256) l[i] = g[i];
  }
  int w = t >> 6;
  int l = t & 63;
  int row_blk = blockIdx.x * 64 + w * 16;
  int arow = row_blk + (l & 15);

  bf16x8 a[4];
  {
    bf16x8 z{};
    const bf16x8* ap =
        (const bf16x8*)(x + (size_t)arow * FDIM + (l >> 4) * 8);
    bool ok = arow < N_NODES;
#pragma unroll
    for (int ks = 0; ks < 4; ++ks) a[ks] = ok ? ap[ks * 4] : z;
  }
  __syncthreads();

  f32x4 acc[8] = {};
#pragma unroll
  for (int ks = 0; ks < 4; ++ks) {
#pragma unroll
    for (int ct = 0; ct < 8; ++ct) {
      int n = ct * 16 + (l & 15);
      int k = ks * 32 + (l >> 4) * 8;
      int ksw = k ^ ((n & 7) << 3);
      bf16x8 b = *(const bf16x8*)&Ws[n * 128 + ksw];
      acc[ct] = __builtin_amdgcn_mfma_f32_16x16x32_bf16(a[ks], b, acc[ct],
                                                        0, 0, 0);
    }
  }

  float bv[8];
#pragma unroll
  for (int ct = 0; ct < 8; ++ct) bv[ct] = bias[ct * 16 + (l & 15)];

#pragma unroll
  for (int r = 0; r < 4; ++r) {
    int row = row_blk + (l >> 4) * 4 + r;
    if (row >= N_NODES) continue;
    if (POOL) {
      int g = batch[row];
#pragma unroll
      for (int ct = 0; ct < 8; ++ct) {
        int col = ct * 16 + (l & 15);
        atomicAdd(&out[(size_t)g * FDIM + col], acc[ct][r] + bv[ct]);
      }
    } else {
#pragma unroll
      for (int ct = 0; ct < 8; ++ct) {
        int col = ct * 16 + (l & 15);
        float v = acc[ct][r] + bv[ct];
        if (RELU) v = fmaxf(v, 0.f);
        y[(size_t)row * FDIM + col] = f2bf(v);
      }
    }
  }
}

extern "C" void kernel_launch(void* const* d_in, const int* in_sizes, int n_in,
                              void* d_out, int out_size, void* d_ws,
                              size_t ws_size, hipStream_t stream) {
  const int* x_type = (const int*)d_in[0];
  const int* edge_index = (const int*)d_in[1];
  const int* batch = (const int*)d_in[2];
  const float* emb = (const float*)d_in[3];
  const float* W1 = (const float*)d_in[4];
  const float* b1 = (const float*)d_in[5];
  const float* W2 = (const float*)d_in[6];
  const float* b2 = (const float*)d_in[7];
  float* out = (float*)d_out;

  const int* src = edge_index;
  const int* dst = edge_index + N_EDGES;

  char* p = (char*)d_ws;
  size_t off = 0;
  auto alloc = [&](size_t bytes) {
    void* r = p + off;
    off = (off + bytes + 255) & ~(size_t)255;
    return r;
  };
  float* dis = (float*)alloc(N_NODES * 4);
  int* cnt = (int*)alloc(N_NODES * 4);
  int* row_ptr = (int*)alloc((N_NODES + 1) * 4);
  int* fill = (int*)alloc(N_NODES * 4);
  int* blk = (int*)alloc(1024);
  int2* csr = (int2*)alloc((size_t)N_EDGES * 8);
  unsigned short* Wt1 = (unsigned short*)alloc(128 * 128 * 2);
  unsigned short* Wt2 = (unsigned short*)alloc(128 * 128 * 2);
  unsigned int* bufA = (unsigned int*)alloc((size_t)N_NODES * 64 * 4);
  unsigned int* bufB = (unsigned int*)alloc((size_t)N_NODES * 64 * 4);
  (void)ws_size;

  k_init<<<256, 256, 0, stream>>>(cnt, fill, out);
  k_count<<<(N_EDGES + 255) / 256, 256, 0, stream>>>(dst, cnt);
  k_scan1<<<NB, 256, 0, stream>>>(cnt, row_ptr, blk);
  k_scan2<<<1, 256, 0, stream>>>(blk);
  k_scan3<<<NB, 256, 0, stream>>>(cnt, row_ptr, blk, dis);
  k_fill<<<(N_EDGES + 255) / 256, 256, 0, stream>>>(src, dst, row_ptr, fill,
                                                    dis, csr);
  k_prep_w<<<128, 256, 0, stream>>>(W1, W2, Wt1, Wt2);
  k_gather<<<(N_NODES * 64 + 255) / 256, 256, 0, stream>>>(x_type, emb, bufA);
  k_agg<<<(N_NODES * 64 + 255) / 256, 256, 0, stream>>>(
      bufA, bufB, row_ptr, csr, dis);
  k_gemm<1, 0><<<(N_NODES + 63) / 64, 256, 0, stream>>>(
      (const unsigned short*)bufB, Wt1, b1, (unsigned short*)bufA, batch, out);
  k_agg<<<(N_NODES * 64 + 255) / 256, 256, 0, stream>>>(
      bufA, bufB, row_ptr, csr, dis);
  k_gemm<0, 1><<<(N_NODES + 63) / 64, 256, 0, stream>>>(
      (const unsigned short*)bufB, Wt2, b2, (unsigned short*)bufA, batch, out);
}